// Round 25
// baseline (87.217 us; speedup 1.0000x reference)
//
#include <hip/hip_runtime.h>

#define BATCH 4
#define SEQ 4096
#define IND 512
#define DH 64
#define NSPLIT 8

typedef __attribute__((ext_vector_type(8))) _Float16 f16x8;
typedef __attribute__((ext_vector_type(4))) _Float16 f16x4;
typedef __attribute__((ext_vector_type(4))) float f32x4;
typedef unsigned long long u64;
typedef unsigned int u32;

#define MFMA16(a, b, c) __builtin_amdgcn_mfma_f32_16x16x32_f16(a, b, c, 0, 0, 0)
#define GLL16(g, l)                                                                  \
    __builtin_amdgcn_global_load_lds(                                                \
        (const __attribute__((address_space(1))) void*)(g),                          \
        (__attribute__((address_space(3))) void*)(l), 16, 0, 0)

// ---- Kernel 0 (fused): blocks <1024 = mask row-ballot; blocks 1024.. = weight prep ----
// mask: wave = one row q, 64 sequential 256B loads, ballot -> bits3[kw][q] (bit j = key).
// wprep: Wt[192][512] f16 n-major k-contig; Q pre-scaled by 0.125*log2(e) (exp2 softmax).
__global__ __launch_bounds__(256) void mask_wprep_kernel(const int* __restrict__ mask,
    u64* __restrict__ bits3,
    const float* __restrict__ Wq, const float* __restrict__ bq,
    const float* __restrict__ Wk, const float* __restrict__ bk,
    const float* __restrict__ Wv, const float* __restrict__ bv,
    _Float16* __restrict__ Wt, float* __restrict__ bcat) {
    __shared__ float tile[64][65];
    const int tid = threadIdx.x;
    if (blockIdx.x < 1024) {
        const int w = tid >> 6, lane = tid & 63;
        const int q = blockIdx.x * 4 + w;
        const int* mp = mask + (size_t)q * SEQ + lane;
        int v[64];
#pragma unroll
        for (int kw = 0; kw < 64; ++kw) v[kw] = mp[kw * 64];  // 64-deep MLP stream
#pragma unroll
        for (int kw = 0; kw < 64; ++kw) {
            u64 b = __ballot(v[kw] != 0);
            if (lane == 0) bits3[((size_t)kw << 12) + q] = b;
        }
        return;
    }
    const int bid = blockIdx.x - 1024;  // 0..23
    const int mat = bid >> 3, k0 = (bid & 7) * 64;
    const float QS = 0.125f * 1.44269504088896f;  // 1/sqrt(64) * log2(e)
    const float* W = (mat == 0) ? Wq : ((mat == 1) ? Wk : Wv);
    const float scale = (mat == 0) ? QS : 1.0f;
    if (bid == 0 && tid < 192) {
        int m2 = tid >> 6, n = tid & 63;
        const float* bb = (m2 == 0) ? bq : ((m2 == 1) ? bk : bv);
        bcat[tid] = bb[n] * ((m2 == 0) ? QS : 1.0f);
    }
    const int n = tid & 63, r0 = tid >> 6;
#pragma unroll
    for (int i = 0; i < 16; ++i) {
        int r = r0 * 16 + i;
        tile[r][n] = W[(size_t)(k0 + r) * 64 + n];
    }
    __syncthreads();
    const int k = tid & 63, n0 = tid >> 6;
#pragma unroll
    for (int i = 0; i < 16; ++i) {
        int nn = n0 * 16 + i;
        Wt[(size_t)(mat * 64 + nn) * IND + k0 + k] = (_Float16)(tile[k][nn] * scale);
    }
}

// ---- Kernel 1: MFMA QKV projection, 32 rows/block, SIX waves (isolated A/B vs R24's
// three): wave w6: matrix = w6>>1, m-tile half = w6&1 -> one 16-row tile per wave.
// 512 blocks x 6 waves = 3072 waves = 3 waves/SIMD (2x TLP). W frags read 2x/block (L2).
// Vt PV-A-frag permutation: position p = 8*g + 4*half + r holds key 16*half + 4*g + r.
__global__ __launch_bounds__(384) void qkv_kernel(const float* __restrict__ X,
    const _Float16* __restrict__ Wt, const float* __restrict__ bcat,
    _Float16* __restrict__ Qh, _Float16* __restrict__ Kh, _Float16* __restrict__ Vt) {
    __shared__ __align__(16) _Float16 xs[32 * 520];  // 33.3 KB
    const int tid = threadIdx.x;
    const int w6 = tid >> 6, lane = tid & 63, l15 = lane & 15, g = lane >> 4;
    const int mat = w6 >> 1, half = w6 & 1;
    const int m0 = blockIdx.x * 32;

    const float4* src = (const float4*)(X + (size_t)m0 * IND);
#pragma unroll
    for (int u = 0; u < 11; ++u) {
        int idx = u * 384 + tid;
        if (idx < 4096) {
            float4 x = src[idx];
            int row = idx >> 7, c4 = idx & 127;  // 128 float4 per row
            f16x4 h;
            h[0] = (_Float16)x.x; h[1] = (_Float16)x.y;
            h[2] = (_Float16)x.z; h[3] = (_Float16)x.w;
            *(f16x4*)&xs[row * 520 + c4 * 4] = h;
        }
    }
    __syncthreads();

    f32x4 acc[4];
#pragma unroll
    for (int nt = 0; nt < 4; ++nt) acc[nt] = (f32x4){0.f, 0.f, 0.f, 0.f};

    const _Float16* Wm = Wt + (size_t)(mat * 64 + l15) * IND + g * 8;
    const int xrow = (half * 16 + l15) * 520;
#pragma unroll
    for (int kc = 0; kc < 16; ++kc) {
        f16x8 a = *(const f16x8*)&xs[xrow + kc * 32 + g * 8];
#pragma unroll
        for (int nt = 0; nt < 4; ++nt)
            acc[nt] = MFMA16(a, *(const f16x8*)(Wm + kc * 32 + (size_t)nt * 16 * IND), acc[nt]);
    }

    const int b = m0 >> 12;
    const int mr = m0 + half * 16;
    const int sbase = m0 & (SEQ - 1);  // 32-aligned block base
#pragma unroll
    for (int nt = 0; nt < 4; ++nt) {
        float bias = bcat[mat * 64 + nt * 16 + l15];
        int ncol = nt * 16 + l15;
        if (mat == 0) {
#pragma unroll
            for (int r = 0; r < 4; ++r)
                Qh[(size_t)(mr + g * 4 + r) * DH + ncol] = (_Float16)(acc[nt][r] + bias);
        } else if (mat == 1) {
#pragma unroll
            for (int r = 0; r < 4; ++r)
                Kh[(size_t)(mr + g * 4 + r) * DH + ncol] = (_Float16)(acc[nt][r] + bias);
        } else {
            f16x4 vv;
#pragma unroll
            for (int r = 0; r < 4; ++r) vv[r] = (_Float16)(acc[nt][r] + bias);
            // keys 16*half+4g+r -> positions 8g+4*half+r
            *(f16x4*)(Vt + ((size_t)b * DH + ncol) * SEQ + sbase + 8 * g + 4 * half) = vv;
        }
    }
}

// ---- Kernel 2: f16 MFMA flash (R20-proven config): KT=64, NSPLIT=8, f32 accP,
// LDS-staged dbuf K/V via global_load_lds, in-register P (swapped QK^T), raw v_exp_f32.
// 512 blocks, 2 blocks/CU: clean FETCH 8MB / WRITE 33MB (R20 counters). Occupancy
// levers closed: 4 blocks/CU thrashes L2 (R12/R13/R21, 19x write amplification).
__global__ __launch_bounds__(256, 2) void flash_kernel(
    const _Float16* __restrict__ Qh, const _Float16* __restrict__ Kh,
    const _Float16* __restrict__ Vt, const u64* __restrict__ bits3,
    float* __restrict__ accP, float* __restrict__ lP) {
    constexpr int KPWT = SEQ / NSPLIT;   // 512 keys per split
    constexpr int NT = KPWT / 64;        // 8 tiles of 64 keys
    __shared__ __align__(16) _Float16 ks[2][64 * 64];  // 8KB/buf
    __shared__ __align__(16) _Float16 vs[2][64 * 64];  // 8KB/buf

    const int tid = threadIdx.x;
    const int w = tid >> 6, lane = tid & 63, l15 = lane & 15, g = lane >> 4;
    const int bid = blockIdx.x;                      // 512 blocks
    const int xcd = bid & 7, i = bid >> 3;           // batch pinned to XCD pair
    const int b = xcd >> 1;
    const int split = (xcd & 1) * 4 + (i & 3);
    const int qblk = i >> 2;                         // 0..15
    const int q0 = qblk * 256 + w * 64;              // 64 q-rows per wave
    const int k0base = split * KPWT;

    const _Float16* Qb = Qh + (size_t)b * SEQ * DH;
    const _Float16* Kb = Kh + (size_t)b * SEQ * DH;
    const _Float16* Vb = Vt + (size_t)b * DH * SEQ;
    const u64* bitsQ = bits3 + q0;

    // staging geometry: per wave-instr 64 lanes x 16B = 1KB; 2 chunks cover 8KB tile
    const int tau = w * 1024 + lane * 16;                 // byte within 4KB chunk 0
    const size_t vg0 = (size_t)(tau >> 7) * (SEQ * 2) + (tau & 127);  // V per-lane base
    _Float16* kl0 = &ks[0][w * 512];
    _Float16* kl1 = &ks[1][w * 512];
    _Float16* vl0 = &vs[0][w * 512];
    _Float16* vl1 = &vs[1][w * 512];

    f16x8 Qa[4][2];
#pragma unroll
    for (int mi = 0; mi < 4; ++mi)
#pragma unroll
        for (int kc = 0; kc < 2; ++kc)
            Qa[mi][kc] = *(const f16x8*)(Qb + (size_t)(q0 + mi * 16 + l15) * DH + kc * 32 + g * 8);

    f32x4 O[4][4];
    float lsum[4];
#pragma unroll
    for (int mi = 0; mi < 4; ++mi)
#pragma unroll
        for (int nd = 0; nd < 4; ++nd) O[mi][nd] = (f32x4){0.f, 0.f, 0.f, 0.f};
#pragma unroll
    for (int j = 0; j < 4; ++j) lsum[j] = 0.f;

    // prologue: stage tile 0 into buf 0
    {
        const char* kg = (const char*)Kb + (size_t)k0base * 128 + tau;
        const char* vg = (const char*)Vb + vg0 + (size_t)k0base * 2;
        GLL16(kg, kl0);
        GLL16(kg + 4096, kl0 + 2048);
        GLL16(vg, vl0);
        GLL16(vg + (size_t)32 * SEQ * 2, vl0 + 2048);
    }
    __syncthreads();

#pragma unroll 2
    for (int t = 0; t < NT; ++t) {
        const int cur = t & 1;
        const int k0 = k0base + t * 64;
        const int kw = k0 >> 6;
        if (t + 1 < NT) {  // stage next tile into other buffer (async, drains at barrier)
            const char* kg = (const char*)Kb + (size_t)(k0 + 64) * 128 + tau;
            const char* vg = (const char*)Vb + vg0 + (size_t)(k0 + 64) * 2;
            _Float16* kl = cur ? kl0 : kl1;
            _Float16* vl = cur ? vl0 : vl1;
            GLL16(kg, kl);
            GLL16(kg + 4096, kl + 2048);
            GLL16(vg, vl);
            GLL16(vg + (size_t)32 * SEQ * 2, vl + 2048);
        }

        // fragments from staged LDS (linear layout, <=2-way conflicts)
        f16x8 Kf[4][2], Vf[4][2];
#pragma unroll
        for (int kk = 0; kk < 4; ++kk)
#pragma unroll
            for (int kc = 0; kc < 2; ++kc)
                Kf[kk][kc] = *(const f16x8*)&ks[cur][(kk * 16 + l15) * 64 + kc * 32 + g * 8];
#pragma unroll
        for (int nd = 0; nd < 4; ++nd)
#pragma unroll
            for (int h = 0; h < 2; ++h)
                Vf[nd][h] = *(const f16x8*)&vs[cur][(nd * 16 + l15) * 64 + h * 32 + g * 8];

#pragma unroll
        for (int mi = 0; mi < 4; ++mi) {
            u64 bw = bitsQ[((size_t)kw << 12) + mi * 16 + l15];  // 64 key bits, this q-row
            f32x4 c0 = {0.f, 0.f, 0.f, 0.f}, c1 = {0.f, 0.f, 0.f, 0.f};
            f32x4 c2 = {0.f, 0.f, 0.f, 0.f}, c3 = {0.f, 0.f, 0.f, 0.f};
            c0 = MFMA16(Kf[0][0], Qa[mi][0], c0);   // swapped: C[key][q], q = l15
            c0 = MFMA16(Kf[0][1], Qa[mi][1], c0);
            c1 = MFMA16(Kf[1][0], Qa[mi][0], c1);
            c1 = MFMA16(Kf[1][1], Qa[mi][1], c1);
            c2 = MFMA16(Kf[2][0], Qa[mi][0], c2);
            c2 = MFMA16(Kf[2][1], Qa[mi][1], c2);
            c3 = MFMA16(Kf[3][0], Qa[mi][0], c3);
            c3 = MFMA16(Kf[3][1], Qa[mi][1], c3);
            u32 ms0 = (u32)(bw >> (4 * g));
            u32 ms1 = (u32)(bw >> (16 + 4 * g));
            u32 ms2 = (u32)(bw >> (32 + 4 * g));
            u32 ms3 = (u32)(bw >> (48 + 4 * g));
            f16x8 Pa0, Pa1;
            float ls = 0.f;
#pragma unroll
            for (int r = 0; r < 4; ++r) {
                // masked -> score 0 -> p = 2^0 = 1.0 (ref: score 1e-6)
                float s0 = ((ms0 >> r) & 1u) ? c0[r] : 0.0f;
                float s1 = ((ms1 >> r) & 1u) ? c1[r] : 0.0f;
                float s2 = ((ms2 >> r) & 1u) ? c2[r] : 0.0f;
                float s3 = ((ms3 >> r) & 1u) ? c3[r] : 0.0f;
                float p0 = __builtin_amdgcn_exp2f(s0);   // raw v_exp_f32
                float p1 = __builtin_amdgcn_exp2f(s1);
                float p2 = __builtin_amdgcn_exp2f(s2);
                float p3 = __builtin_amdgcn_exp2f(s3);
                ls += (p0 + p1) + (p2 + p3);
                Pa0[r] = (_Float16)p0;
                Pa0[r + 4] = (_Float16)p1;
                Pa1[r] = (_Float16)p2;
                Pa1[r + 4] = (_Float16)p3;
            }
            lsum[mi] += ls;
#pragma unroll
            for (int nd = 0; nd < 4; ++nd) {
                O[mi][nd] = MFMA16(Pa0, Vf[nd][0], O[mi][nd]);
                O[mi][nd] = MFMA16(Pa1, Vf[nd][1], O[mi][nd]);
            }
        }
        __syncthreads();  // drains staging vmcnt + guards buffer reuse (m97 pattern)
    }

    // row-sum: lane's q = l15 (+mi*16); reduce over g (lane bits 4,5)
#pragma unroll
    for (int j = 0; j < 4; ++j) {
        float v = lsum[j];
        v += __shfl_xor(v, 16);
        v += __shfl_xor(v, 32);
        lsum[j] = v;
    }
    float* accB = accP + ((size_t)split * BATCH + b) * SEQ * DH;
    float* lB = lP + ((size_t)split * BATCH + b) * SEQ;
    if (lane < 16) {
#pragma unroll
        for (int mi = 0; mi < 4; ++mi)
            lB[q0 + mi * 16 + l15] = lsum[mi];
    }
#pragma unroll
    for (int mi = 0; mi < 4; ++mi)
#pragma unroll
        for (int nd = 0; nd < 4; ++nd)
#pragma unroll
            for (int r = 0; r < 4; ++r)
                accB[(size_t)(q0 + mi * 16 + 4 * g + r) * DH + nd * 16 + l15] = O[mi][nd][r];
}

// ---- Kernel 3: combine key-splits: out = sum(acc)/sum(l), 2 outputs/thread (float2) ----
__global__ __launch_bounds__(256) void reduce_kernel(const float* __restrict__ accP,
                                                     const float* __restrict__ lP,
                                                     float* __restrict__ out) {
    int idx = blockIdx.x * 256 + threadIdx.x;  // over B*S*DH/2
    int bq = idx >> 5, d2 = idx & 31;
    float a0 = 0.f, a1 = 0.f, l = 0.f;
#pragma unroll
    for (int s = 0; s < NSPLIT; ++s) {
        float2 v = *(const float2*)&accP[((size_t)s * BATCH * SEQ + bq) * DH + d2 * 2];
        a0 += v.x;
        a1 += v.y;
        l += lP[(size_t)s * BATCH * SEQ + bq];
    }
    float inv = 1.0f / l;
    float2 o = make_float2(a0 * inv, a1 * inv);
    *(float2*)&out[(size_t)idx * 2] = o;
}

extern "C" void kernel_launch(void* const* d_in, const int* in_sizes, int n_in,
                              void* d_out, int out_size, void* d_ws, size_t ws_size,
                              hipStream_t stream) {
    const float* X = (const float*)d_in[0];
    const int* mask = (const int*)d_in[1];
    const float* Wq = (const float*)d_in[2];
    const float* bq = (const float*)d_in[3];
    const float* Wk = (const float*)d_in[4];
    const float* bk = (const float*)d_in[5];
    const float* Wv = (const float*)d_in[6];
    const float* bv = (const float*)d_in[7];
    float* out = (float*)d_out;

    char* ws = (char*)d_ws;
    _Float16* Qh = (_Float16*)ws;                       // 2 MB
    _Float16* Kh = (_Float16*)(ws + (2u << 20));        // 2 MB
    _Float16* Vt = (_Float16*)(ws + (4u << 20));        // 2 MB (pi-permuted keys)
    u64* bits3 = (u64*)(ws + (6u << 20));               // 2 MB [kw][q]
    float* accP = (float*)(ws + (8u << 20));            // 32 MB (8 splits, f32)
    float* lP = (float*)(ws + (40u << 20));             // 512 KB
    _Float16* Wt = (_Float16*)(ws + (41u << 20));       // 192 KB
    float* bcat = (float*)(ws + (41u << 20) + (256u << 10));  // 768 B

    mask_wprep_kernel<<<dim3(1048), dim3(256), 0, stream>>>(mask, bits3, Wq, bq, Wk, bk,
                                                            Wv, bv, Wt, bcat);
    qkv_kernel<<<dim3(512), dim3(384), 0, stream>>>(X, Wt, bcat, Qh, Kh, Vt);
    flash_kernel<<<dim3(512), dim3(256), 0, stream>>>(Qh, Kh, Vt, bits3, accP, lP);
    reduce_kernel<<<dim3(BATCH * SEQ * DH / 512), dim3(256), 0, stream>>>(accP, lP, out);
}

// Round 26
// 74.613 us; speedup vs baseline: 1.1689x; 1.1689x over previous
//
#include <hip/hip_runtime.h>

#define BATCH 4
#define SEQ 4096
#define IND 512
#define DH 64
#define NSPLIT 8

typedef __attribute__((ext_vector_type(8))) _Float16 f16x8;
typedef __attribute__((ext_vector_type(4))) _Float16 f16x4;
typedef __attribute__((ext_vector_type(2))) _Float16 f16x2;
typedef __attribute__((ext_vector_type(4))) float f32x4;
typedef unsigned long long u64;
typedef unsigned int u32;

#define MFMA16(a, b, c) __builtin_amdgcn_mfma_f32_16x16x32_f16(a, b, c, 0, 0, 0)
#define GLL16(g, l)                                                                  \
    __builtin_amdgcn_global_load_lds(                                                \
        (const __attribute__((address_space(1))) void*)(g),                          \
        (__attribute__((address_space(3))) void*)(l), 16, 0, 0)

// ---- Kernel 0 (fused): blocks <1024 = mask row-ballot; blocks 1024.. = weight prep ----
// mask: wave = one row q, 64 sequential 256B loads, ballot -> bits3[kw][q] (bit j = key).
// wprep: Wt[192][512] f16 n-major k-contig; Q pre-scaled by 0.125*log2(e) (exp2 softmax).
__global__ __launch_bounds__(256) void mask_wprep_kernel(const int* __restrict__ mask,
    u64* __restrict__ bits3,
    const float* __restrict__ Wq, const float* __restrict__ bq,
    const float* __restrict__ Wk, const float* __restrict__ bk,
    const float* __restrict__ Wv, const float* __restrict__ bv,
    _Float16* __restrict__ Wt, float* __restrict__ bcat) {
    __shared__ float tile[64][65];
    const int tid = threadIdx.x;
    if (blockIdx.x < 1024) {
        const int w = tid >> 6, lane = tid & 63;
        const int q = blockIdx.x * 4 + w;
        const int* mp = mask + (size_t)q * SEQ + lane;
        int v[64];
#pragma unroll
        for (int kw = 0; kw < 64; ++kw) v[kw] = mp[kw * 64];  // 64-deep MLP stream
#pragma unroll
        for (int kw = 0; kw < 64; ++kw) {
            u64 b = __ballot(v[kw] != 0);
            if (lane == 0) bits3[((size_t)kw << 12) + q] = b;
        }
        return;
    }
    const int bid = blockIdx.x - 1024;  // 0..23
    const int mat = bid >> 3, k0 = (bid & 7) * 64;
    const float QS = 0.125f * 1.44269504088896f;  // 1/sqrt(64) * log2(e)
    const float* W = (mat == 0) ? Wq : ((mat == 1) ? Wk : Wv);
    const float scale = (mat == 0) ? QS : 1.0f;
    if (bid == 0 && tid < 192) {
        int m2 = tid >> 6, n = tid & 63;
        const float* bb = (m2 == 0) ? bq : ((m2 == 1) ? bk : bv);
        bcat[tid] = bb[n] * ((m2 == 0) ? QS : 1.0f);
    }
    const int n = tid & 63, r0 = tid >> 6;
#pragma unroll
    for (int i = 0; i < 16; ++i) {
        int r = r0 * 16 + i;
        tile[r][n] = W[(size_t)(k0 + r) * 64 + n];
    }
    __syncthreads();
    const int k = tid & 63, n0 = tid >> 6;
#pragma unroll
    for (int i = 0; i < 16; ++i) {
        int nn = n0 * 16 + i;
        Wt[(size_t)(mat * 64 + nn) * IND + k0 + k] = (_Float16)(tile[k][nn] * scale);
    }
}

// ---- Kernel 1: MFMA QKV projection, 32 rows/block, 3 waves (wave w = matrix w),
// each wave computes TWO 16-row m-tiles sharing W fragments (R24-proven; 6-wave
// variant regressed -10us in isolated A/B R25).
// Vt PV-A-frag permutation: position p = 8*g + 4*hi + r holds key 16*hi + 4*g + r.
__global__ __launch_bounds__(192) void qkv_kernel(const float* __restrict__ X,
    const _Float16* __restrict__ Wt, const float* __restrict__ bcat,
    _Float16* __restrict__ Qh, _Float16* __restrict__ Kh, _Float16* __restrict__ Vt) {
    __shared__ __align__(16) _Float16 xs[32 * 520];  // 33.3 KB
    const int tid = threadIdx.x;
    const int w = tid >> 6, lane = tid & 63, l15 = lane & 15, g = lane >> 4;
    const int m0 = blockIdx.x * 32;

    const float4* src = (const float4*)(X + (size_t)m0 * IND);
#pragma unroll
    for (int u = 0; u < 22; ++u) {
        int idx = u * 192 + tid;
        if (idx < 4096) {
            float4 x = src[idx];
            int row = idx >> 7, c4 = idx & 127;  // 128 float4 per row
            f16x4 h;
            h[0] = (_Float16)x.x; h[1] = (_Float16)x.y;
            h[2] = (_Float16)x.z; h[3] = (_Float16)x.w;
            *(f16x4*)&xs[row * 520 + c4 * 4] = h;
        }
    }
    __syncthreads();

    f32x4 acc0[4], acc1[4];
#pragma unroll
    for (int nt = 0; nt < 4; ++nt) {
        acc0[nt] = (f32x4){0.f, 0.f, 0.f, 0.f};
        acc1[nt] = (f32x4){0.f, 0.f, 0.f, 0.f};
    }

    const _Float16* Wm = Wt + (size_t)(w * 64 + l15) * IND + g * 8;
#pragma unroll
    for (int kc = 0; kc < 16; ++kc) {
        f16x8 a0 = *(const f16x8*)&xs[l15 * 520 + kc * 32 + g * 8];
        f16x8 a1 = *(const f16x8*)&xs[(16 + l15) * 520 + kc * 32 + g * 8];
#pragma unroll
        for (int nt = 0; nt < 4; ++nt) {
            f16x8 wf = *(const f16x8*)(Wm + kc * 32 + (size_t)nt * 16 * IND);
            acc0[nt] = MFMA16(a0, wf, acc0[nt]);
            acc1[nt] = MFMA16(a1, wf, acc1[nt]);
        }
    }

    const int b = m0 >> 12;
    const int sbase = m0 & (SEQ - 1);  // 32-aligned block base
#pragma unroll
    for (int nt = 0; nt < 4; ++nt) {
        float bias = bcat[w * 64 + nt * 16 + l15];
        int ncol = nt * 16 + l15;
        if (w == 0) {
#pragma unroll
            for (int r = 0; r < 4; ++r) {
                Qh[(size_t)(m0 + g * 4 + r) * DH + ncol] = (_Float16)(acc0[nt][r] + bias);
                Qh[(size_t)(m0 + 16 + g * 4 + r) * DH + ncol] = (_Float16)(acc1[nt][r] + bias);
            }
        } else if (w == 1) {
#pragma unroll
            for (int r = 0; r < 4; ++r) {
                Kh[(size_t)(m0 + g * 4 + r) * DH + ncol] = (_Float16)(acc0[nt][r] + bias);
                Kh[(size_t)(m0 + 16 + g * 4 + r) * DH + ncol] = (_Float16)(acc1[nt][r] + bias);
            }
        } else {
            f16x4 v0, v1;
#pragma unroll
            for (int r = 0; r < 4; ++r) {
                v0[r] = (_Float16)(acc0[nt][r] + bias);  // keys 4g+r    (hi=0)
                v1[r] = (_Float16)(acc1[nt][r] + bias);  // keys 16+4g+r (hi=1)
            }
            _Float16* vb = Vt + ((size_t)b * DH + ncol) * SEQ + sbase + 8 * g;
            *(f16x4*)(vb) = v0;      // positions 8g+0..3
            *(f16x4*)(vb + 4) = v1;  // positions 8g+4..7
        }
    }
}

// ---- Kernel 2: f16 MFMA flash (R20-proven core + f16 partials, isolated A/B vs R24):
// KT=64, NSPLIT=8, LDS-staged dbuf K/V via global_load_lds, in-register P, raw v_exp_f32.
// 512 blocks, 2 blocks/CU (occupancy closed: 4/CU thrashes L2 3x). f16 accP halves
// partial traffic; R23-vs-R25 delta indicates ~-3us at clean residency.
__global__ __launch_bounds__(256, 2) void flash_kernel(
    const _Float16* __restrict__ Qh, const _Float16* __restrict__ Kh,
    const _Float16* __restrict__ Vt, const u64* __restrict__ bits3,
    _Float16* __restrict__ accP, float* __restrict__ lP) {
    constexpr int KPWT = SEQ / NSPLIT;   // 512 keys per split
    constexpr int NT = KPWT / 64;        // 8 tiles of 64 keys
    __shared__ __align__(16) _Float16 ks[2][64 * 64];  // 8KB/buf
    __shared__ __align__(16) _Float16 vs[2][64 * 64];  // 8KB/buf

    const int tid = threadIdx.x;
    const int w = tid >> 6, lane = tid & 63, l15 = lane & 15, g = lane >> 4;
    const int bid = blockIdx.x;                      // 512 blocks
    const int xcd = bid & 7, i = bid >> 3;           // batch pinned to XCD pair
    const int b = xcd >> 1;
    const int split = (xcd & 1) * 4 + (i & 3);
    const int qblk = i >> 2;                         // 0..15
    const int q0 = qblk * 256 + w * 64;              // 64 q-rows per wave
    const int k0base = split * KPWT;

    const _Float16* Qb = Qh + (size_t)b * SEQ * DH;
    const _Float16* Kb = Kh + (size_t)b * SEQ * DH;
    const _Float16* Vb = Vt + (size_t)b * DH * SEQ;
    const u64* bitsQ = bits3 + q0;

    // staging geometry: per wave-instr 64 lanes x 16B = 1KB; 2 chunks cover 8KB tile
    const int tau = w * 1024 + lane * 16;                 // byte within 4KB chunk 0
    const size_t vg0 = (size_t)(tau >> 7) * (SEQ * 2) + (tau & 127);  // V per-lane base
    _Float16* kl0 = &ks[0][w * 512];
    _Float16* kl1 = &ks[1][w * 512];
    _Float16* vl0 = &vs[0][w * 512];
    _Float16* vl1 = &vs[1][w * 512];

    f16x8 Qa[4][2];
#pragma unroll
    for (int mi = 0; mi < 4; ++mi)
#pragma unroll
        for (int kc = 0; kc < 2; ++kc)
            Qa[mi][kc] = *(const f16x8*)(Qb + (size_t)(q0 + mi * 16 + l15) * DH + kc * 32 + g * 8);

    f32x4 O[4][4];
    float lsum[4];
#pragma unroll
    for (int mi = 0; mi < 4; ++mi)
#pragma unroll
        for (int nd = 0; nd < 4; ++nd) O[mi][nd] = (f32x4){0.f, 0.f, 0.f, 0.f};
#pragma unroll
    for (int j = 0; j < 4; ++j) lsum[j] = 0.f;

    // prologue: stage tile 0 into buf 0
    {
        const char* kg = (const char*)Kb + (size_t)k0base * 128 + tau;
        const char* vg = (const char*)Vb + vg0 + (size_t)k0base * 2;
        GLL16(kg, kl0);
        GLL16(kg + 4096, kl0 + 2048);
        GLL16(vg, vl0);
        GLL16(vg + (size_t)32 * SEQ * 2, vl0 + 2048);
    }
    __syncthreads();

#pragma unroll 2
    for (int t = 0; t < NT; ++t) {
        const int cur = t & 1;
        const int k0 = k0base + t * 64;
        const int kw = k0 >> 6;
        if (t + 1 < NT) {  // stage next tile into other buffer (async, drains at barrier)
            const char* kg = (const char*)Kb + (size_t)(k0 + 64) * 128 + tau;
            const char* vg = (const char*)Vb + vg0 + (size_t)(k0 + 64) * 2;
            _Float16* kl = cur ? kl0 : kl1;
            _Float16* vl = cur ? vl0 : vl1;
            GLL16(kg, kl);
            GLL16(kg + 4096, kl + 2048);
            GLL16(vg, vl);
            GLL16(vg + (size_t)32 * SEQ * 2, vl + 2048);
        }

        // fragments from staged LDS (linear layout, <=2-way conflicts)
        f16x8 Kf[4][2], Vf[4][2];
#pragma unroll
        for (int kk = 0; kk < 4; ++kk)
#pragma unroll
            for (int kc = 0; kc < 2; ++kc)
                Kf[kk][kc] = *(const f16x8*)&ks[cur][(kk * 16 + l15) * 64 + kc * 32 + g * 8];
#pragma unroll
        for (int nd = 0; nd < 4; ++nd)
#pragma unroll
            for (int h = 0; h < 2; ++h)
                Vf[nd][h] = *(const f16x8*)&vs[cur][(nd * 16 + l15) * 64 + h * 32 + g * 8];

#pragma unroll
        for (int mi = 0; mi < 4; ++mi) {
            u64 bw = bitsQ[((size_t)kw << 12) + mi * 16 + l15];  // 64 key bits, this q-row
            f32x4 c0 = {0.f, 0.f, 0.f, 0.f}, c1 = {0.f, 0.f, 0.f, 0.f};
            f32x4 c2 = {0.f, 0.f, 0.f, 0.f}, c3 = {0.f, 0.f, 0.f, 0.f};
            c0 = MFMA16(Kf[0][0], Qa[mi][0], c0);   // swapped: C[key][q], q = l15
            c0 = MFMA16(Kf[0][1], Qa[mi][1], c0);
            c1 = MFMA16(Kf[1][0], Qa[mi][0], c1);
            c1 = MFMA16(Kf[1][1], Qa[mi][1], c1);
            c2 = MFMA16(Kf[2][0], Qa[mi][0], c2);
            c2 = MFMA16(Kf[2][1], Qa[mi][1], c2);
            c3 = MFMA16(Kf[3][0], Qa[mi][0], c3);
            c3 = MFMA16(Kf[3][1], Qa[mi][1], c3);
            u32 ms0 = (u32)(bw >> (4 * g));
            u32 ms1 = (u32)(bw >> (16 + 4 * g));
            u32 ms2 = (u32)(bw >> (32 + 4 * g));
            u32 ms3 = (u32)(bw >> (48 + 4 * g));
            f16x8 Pa0, Pa1;
            float ls = 0.f;
#pragma unroll
            for (int r = 0; r < 4; ++r) {
                // masked -> score 0 -> p = 2^0 = 1.0 (ref: score 1e-6)
                float s0 = ((ms0 >> r) & 1u) ? c0[r] : 0.0f;
                float s1 = ((ms1 >> r) & 1u) ? c1[r] : 0.0f;
                float s2 = ((ms2 >> r) & 1u) ? c2[r] : 0.0f;
                float s3 = ((ms3 >> r) & 1u) ? c3[r] : 0.0f;
                float p0 = __builtin_amdgcn_exp2f(s0);   // raw v_exp_f32
                float p1 = __builtin_amdgcn_exp2f(s1);
                float p2 = __builtin_amdgcn_exp2f(s2);
                float p3 = __builtin_amdgcn_exp2f(s3);
                ls += (p0 + p1) + (p2 + p3);
                Pa0[r] = (_Float16)p0;
                Pa0[r + 4] = (_Float16)p1;
                Pa1[r] = (_Float16)p2;
                Pa1[r + 4] = (_Float16)p3;
            }
            lsum[mi] += ls;
#pragma unroll
            for (int nd = 0; nd < 4; ++nd) {
                O[mi][nd] = MFMA16(Pa0, Vf[nd][0], O[mi][nd]);
                O[mi][nd] = MFMA16(Pa1, Vf[nd][1], O[mi][nd]);
            }
        }
        __syncthreads();  // drains staging vmcnt + guards buffer reuse (m97 pattern)
    }

    // row-sum: lane's q = l15 (+mi*16); reduce over g (lane bits 4,5)
#pragma unroll
    for (int j = 0; j < 4; ++j) {
        float v = lsum[j];
        v += __shfl_xor(v, 16);
        v += __shfl_xor(v, 32);
        lsum[j] = v;
    }
    _Float16* accB = accP + ((size_t)split * BATCH + b) * SEQ * DH;
    float* lB = lP + ((size_t)split * BATCH + b) * SEQ;
    if (lane < 16) {
#pragma unroll
        for (int mi = 0; mi < 4; ++mi)
            lB[q0 + mi * 16 + l15] = lsum[mi];
    }
#pragma unroll
    for (int mi = 0; mi < 4; ++mi)
#pragma unroll
        for (int nd = 0; nd < 4; ++nd)
#pragma unroll
            for (int r = 0; r < 4; ++r)
                accB[(size_t)(q0 + mi * 16 + 4 * g + r) * DH + nd * 16 + l15] =
                    (_Float16)O[mi][nd][r];
}

// ---- Kernel 3: combine key-splits: out = sum(acc_f16)/sum(l), 2 outputs/thread ----
__global__ __launch_bounds__(256) void reduce_kernel(const _Float16* __restrict__ accP,
                                                     const float* __restrict__ lP,
                                                     float* __restrict__ out) {
    int idx = blockIdx.x * 256 + threadIdx.x;  // over B*S*DH/2
    int bq = idx >> 5, d2 = idx & 31;
    float a0 = 0.f, a1 = 0.f, l = 0.f;
#pragma unroll
    for (int s = 0; s < NSPLIT; ++s) {
        f16x2 v = *(const f16x2*)&accP[((size_t)s * BATCH * SEQ + bq) * DH + d2 * 2];
        a0 += (float)v[0];
        a1 += (float)v[1];
        l += lP[(size_t)s * BATCH * SEQ + bq];
    }
    float inv = 1.0f / l;
    float2 o = make_float2(a0 * inv, a1 * inv);
    *(float2*)&out[(size_t)idx * 2] = o;
}

extern "C" void kernel_launch(void* const* d_in, const int* in_sizes, int n_in,
                              void* d_out, int out_size, void* d_ws, size_t ws_size,
                              hipStream_t stream) {
    const float* X = (const float*)d_in[0];
    const int* mask = (const int*)d_in[1];
    const float* Wq = (const float*)d_in[2];
    const float* bq = (const float*)d_in[3];
    const float* Wk = (const float*)d_in[4];
    const float* bk = (const float*)d_in[5];
    const float* Wv = (const float*)d_in[6];
    const float* bv = (const float*)d_in[7];
    float* out = (float*)d_out;

    char* ws = (char*)d_ws;
    _Float16* Qh = (_Float16*)ws;                       // 2 MB
    _Float16* Kh = (_Float16*)(ws + (2u << 20));        // 2 MB
    _Float16* Vt = (_Float16*)(ws + (4u << 20));        // 2 MB (pi-permuted keys)
    u64* bits3 = (u64*)(ws + (6u << 20));               // 2 MB [kw][q]
    _Float16* accP = (_Float16*)(ws + (8u << 20));      // 16 MB (8 splits, f16)
    float* lP = (float*)(ws + (24u << 20));             // 512 KB
    _Float16* Wt = (_Float16*)(ws + (25u << 20));       // 192 KB
    float* bcat = (float*)(ws + (25u << 20) + (256u << 10));  // 768 B

    mask_wprep_kernel<<<dim3(1048), dim3(256), 0, stream>>>(mask, bits3, Wq, bq, Wk, bk,
                                                            Wv, bv, Wt, bcat);
    qkv_kernel<<<dim3(512), dim3(192), 0, stream>>>(X, Wt, bcat, Qh, Kh, Vt);
    flash_kernel<<<dim3(512), dim3(256), 0, stream>>>(Qh, Kh, Vt, bits3, accP, lP);
    reduce_kernel<<<dim3(BATCH * SEQ * DH / 512), dim3(256), 0, stream>>>(accP, lP, out);
}